// Round 9
// baseline (243.703 us; speedup 1.0000x reference)
//
#include <hip/hip_runtime.h>

// Full 2D convolution: in (32,16,256,256) f32, shared 5x5 kernel, out (32,16,260,260) f32.
// out[n][y][x] = sum_{a,b in [0,5)} in[n][y-a][x-b] * w[a][b]
//
// R8: recombination of measured wins.
//  - R4c (ROWS=4, depth-3 prefetch pipeline) measured 80% occupancy -- but its
//    (256,8) bound squeezed regs to 32 -> spill -> regression.
//  - R7b (ROWS=5, load-then-consume, dep distance ~1 row) measured only 45%
//    occupancy at 48 regs, VALUBusy 35%, 2.7 TB/s vs the 6.24 TB/s the harness
//    fills prove: per-wave ILP is the differentiator, waves stall per-row.
//  - R8 = R4c's pipeline structure under the proven-safe (256,4) cap (64 regs):
//    demand ~= raw 2x3x4=24 + acc 16 + v 8 + addr ~12 ~= 60 <= 64, no spill.
//    Each wave holds 6 loads in flight while FMA-ing -> 3x latency tolerance
//    on top of 8-wave TLP. NT stores kept from R7b (FETCH 81k, best measured).
//  - Tripwire: WRITE_SIZE > 150k KB => spill => revert to R7b structure.
//  - Weights in SGPRs via readfirstlane; clamped-load + cndmask edges
//    (verified in R3/R4c/R5b/R6/R7b).

#define IMG 256
#define OW  260
#define TXN 65            // float4s per output row
#define ROWS 4            // output rows per thread
#define IROWS 8           // input rows touched: ROWS + 4
#define STRIPS 65         // 260 / 4
#define NIMG 512          // 32*16 images
#define NTHREADS (NIMG * STRIPS * TXN)   // 512*65*65 = 2,163,200 = 8450 * 256

typedef float f32x4 __attribute__((ext_vector_type(4)));

#define ISSUE(rr)                                                         \
    {                                                                     \
        int yy = y0 + (rr) - 4;                                           \
        int yc = yy < 0 ? 0 : (yy > IMG - 1 ? IMG - 1 : yy);              \
        const float* rb = img + yc * IMG;                                 \
        rawL[(rr) & 3] = *(const float4*)(rb + xl);                       \
        rawH[(rr) & 3] = *(const float4*)(rb + xh);                       \
    }

__global__ __launch_bounds__(256, 4) void conv_full_pipe8(
    const float* __restrict__ in, const float* __restrict__ w,
    float* __restrict__ out)
{
    // ---- Weights: wave-uniform -> force into SGPRs.
    float wt[25];
#pragma unroll
    for (int i = 0; i < 25; ++i)
        wt[i] = __int_as_float(__builtin_amdgcn_readfirstlane(__float_as_int(w[i])));

    int idx = blockIdx.x * 256 + threadIdx.x;
    int tx4 = idx % TXN;
    int t   = idx / TXN;
    int s   = t % STRIPS;
    int n   = t / STRIPS;
    int y0  = s * ROWS;
    int x0  = tx4 * 4;

    // Clamped, always-in-bounds 16B-aligned load columns.
    int xl = x0 - 4; if (xl < 0) xl = 0;
    int xh = x0;     if (xh > IMG - 4) xh = IMG - 4;
    const bool zL = (tx4 == 0);         // cols x0-4..x0-1 left of image
    const bool zR = (tx4 == TXN - 1);   // cols 256..259 right of image

    const float* img = in + (size_t)n * (IMG * IMG);

    // Ring buffer of 4 rows (indexed rr&3), 3 rows prefetched ahead.
    float4 rawL[4], rawH[4];
    ISSUE(0); ISSUE(1); ISSUE(2);

    float acc[ROWS][4];
#pragma unroll
    for (int r = 0; r < ROWS; ++r)
        acc[r][0] = acc[r][1] = acc[r][2] = acc[r][3] = 0.f;

#pragma unroll
    for (int rr = 0; rr < IROWS; ++rr) {
        if (rr + 3 < IROWS) ISSUE(rr + 3);   // keep 3 rows (6 loads) in flight

        // Branch-free masking of this input row into an 8-wide window.
        int yy = y0 + rr - 4;
        bool rv = (yy >= 0) & (yy < IMG);
        bool mL = rv & !zL;
        bool mR = rv & !zR;
        float4 rl = rawL[rr & 3];
        float4 rh = rawH[rr & 3];
        float v[8];
        v[0] = mL ? rl.x : 0.f;
        v[1] = mL ? rl.y : 0.f;
        v[2] = mL ? rl.z : 0.f;
        v[3] = mL ? rl.w : 0.f;
        v[4] = mR ? rh.x : 0.f;
        v[5] = mR ? rh.y : 0.f;
        v[6] = mR ? rh.z : 0.f;
        v[7] = mR ? rh.w : 0.f;

        // Input row y0+rr-4 feeds output rows r with a = r-rr+4 in [0,4].
#pragma unroll
        for (int r = 0; r < ROWS; ++r) {
            const int a = r - rr + 4;
            if (a >= 0 && a <= 4) {
#pragma unroll
                for (int b = 0; b < 5; ++b) {
                    float wv = wt[a * 5 + b];
                    acc[r][0] = fmaf(v[4 - b], wv, acc[r][0]);
                    acc[r][1] = fmaf(v[5 - b], wv, acc[r][1]);
                    acc[r][2] = fmaf(v[6 - b], wv, acc[r][2]);
                    acc[r][3] = fmaf(v[7 - b], wv, acc[r][3]);
                }
            }
        }
    }

    // ---- Store 4 output rows, one non-temporal 16B store each.
    float* outp = out + (((size_t)n * OW + y0) * TXN + tx4) * 4;
#pragma unroll
    for (int r = 0; r < ROWS; ++r) {
        f32x4 val = { acc[r][0], acc[r][1], acc[r][2], acc[r][3] };
        __builtin_nontemporal_store(val, (f32x4*)(outp + (size_t)r * OW));
    }
}

extern "C" void kernel_launch(void* const* d_in, const int* in_sizes, int n_in,
                              void* d_out, int out_size, void* d_ws, size_t ws_size,
                              hipStream_t stream) {
    const float* in = (const float*)d_in[0];   // 32*16*256*256 f32
    const float* w  = (const float*)d_in[1];   // 5*5 f32
    float* out = (float*)d_out;                // 32*16*260*260 f32

    int blocks = NTHREADS / 256;               // exactly 8450
    conv_full_pipe8<<<blocks, 256, 0, stream>>>(in, w, out);
}